// Round 1
// baseline (937.202 us; speedup 1.0000x reference)
//
#include <hip/hip_runtime.h>

// LKalmanFilter: B=32 blocks, N=2048.
// out = concat(new_w [32*2048], P_new [32*2048*2048]) fp32.
// Memory-bound: P is 512 MiB; floor = 2 reads + 1 write of P ~= 1.5 GiB.

#define LAMBDA 0.98f
#define NB 32
#define NN 2048
#define NROWS (NB * NN)                 // 65536
#define ROWS_PER_BLOCK 16
#define K1_BLOCKS (NROWS / ROWS_PER_BLOCK)  // 4096

// ---- K1: PH[row] = P[row,:] . H[b,:]  + per-block partial of sum(H*PH) ----
__global__ __launch_bounds__(256) void k1_gemv(const float* __restrict__ P,
                                               const float* __restrict__ H,
                                               float* __restrict__ PH,
                                               float* __restrict__ partial) {
    const int wave = threadIdx.x >> 6;
    const int lane = threadIdx.x & 63;
    __shared__ float wsum[4];
    float part = 0.f;
    const int row0 = blockIdx.x * ROWS_PER_BLOCK + wave * 4;
    for (int r = 0; r < 4; ++r) {
        const int row = row0 + r;
        const int b = row >> 11;                       // row / 2048
        const float4* __restrict__ prow = (const float4*)(P + (size_t)row * NN);
        const float4* __restrict__ h4   = (const float4*)(H + b * NN);
        float s = 0.f;
        #pragma unroll
        for (int jj = 0; jj < 8; ++jj) {               // 64 lanes * 8 * float4 = 2048
            const float4 p  = prow[lane + 64 * jj];
            const float4 hv = h4[lane + 64 * jj];
            s += p.x * hv.x + p.y * hv.y + p.z * hv.z + p.w * hv.w;
        }
        #pragma unroll
        for (int off = 32; off > 0; off >>= 1) s += __shfl_down(s, off, 64);
        if (lane == 0) {
            PH[row] = s;
            part += H[row] * s;                        // H flat index == row
        }
    }
    if (lane == 0) wsum[wave] = part;
    __syncthreads();
    if (threadIdx.x == 0)
        partial[blockIdx.x] = wsum[0] + wsum[1] + wsum[2] + wsum[3];
}

// ---- K2: reduce 4096 partials -> tmp (single block, overwrites, no init) ----
__global__ __launch_bounds__(256) void k2_reduce(const float* __restrict__ partial,
                                                 float* __restrict__ tmp) {
    float s = 0.f;
    for (int i = threadIdx.x; i < K1_BLOCKS; i += 256) s += partial[i];
    #pragma unroll
    for (int off = 32; off > 0; off >>= 1) s += __shfl_down(s, off, 64);
    __shared__ float wsum[4];
    const int wave = threadIdx.x >> 6;
    const int lane = threadIdx.x & 63;
    if (lane == 0) wsum[wave] = s;
    __syncthreads();
    if (threadIdx.x == 0) tmp[0] = wsum[0] + wsum[1] + wsum[2] + wsum[3];
}

// ---- K3: new_w and P_new, flat float4 grid ----
// idx in [0, 16384): new_w float4s. idx >= 16384: P_new float4s (linear order).
__global__ __launch_bounds__(256) void k3_update(const float* __restrict__ P,
                                                 const float* __restrict__ w,
                                                 const float* __restrict__ err_p,
                                                 const float* __restrict__ PH,
                                                 const float* __restrict__ tmp,
                                                 float* __restrict__ out) {
    const float A = 1.0f / (32.0f * LAMBDA + tmp[0]);
    const unsigned idx = blockIdx.x * 256u + threadIdx.x;
    if (idx < 16384u) {
        const float ke = A * err_p[0];
        const float4 w4 = ((const float4*)w)[idx];
        const float4 ph = ((const float4*)PH)[idx];
        float4 o;
        o.x = w4.x + ph.x * ke;
        o.y = w4.y + ph.y * ke;
        o.z = w4.z + ph.z * ke;
        o.w = w4.w + ph.w * ke;
        ((float4*)out)[idx] = o;
    } else {
        const float invLam = 1.0f / LAMBDA;
        const unsigned linear = idx - 16384u;          // float4 index into P
        const unsigned b   = linear >> 20;             // NN*NN/4 = 2^20 float4 per block
        const unsigned rem = linear & 0xFFFFFu;
        const unsigned i   = rem >> 9;                 // NN/4 = 512 float4 per row
        const unsigned j4  = rem & 511u;
        const float k_i = PH[(b << 11) + i] * A;       // K_i
        const float4 p4  = ((const float4*)P)[linear];
        const float4 ph4 = ((const float4*)(PH + (b << 11)))[j4];  // HtP_j == PH_j (P symmetric)
        float4 o;
        o.x = (p4.x - k_i * ph4.x) * invLam;
        o.y = (p4.y - k_i * ph4.y) * invLam;
        o.z = (p4.z - k_i * ph4.z) * invLam;
        o.w = (p4.w - k_i * ph4.w) * invLam;
        ((float4*)(out + NROWS))[linear] = o;
    }
}

extern "C" void kernel_launch(void* const* d_in, const int* in_sizes, int n_in,
                              void* d_out, int out_size, void* d_ws, size_t ws_size,
                              hipStream_t stream) {
    const float* P   = (const float*)d_in[0];   // [32,2048,2048]
    const float* H   = (const float*)d_in[1];   // [32,2048]
    const float* w   = (const float*)d_in[2];   // [32,2048]
    const float* err = (const float*)d_in[3];   // scalar
    float* out = (float*)d_out;
    float* ws  = (float*)d_ws;

    float* tmp     = ws;             // 1 float
    float* partial = ws + 64;        // 4096 floats
    float* PH      = ws + 64 + 4096; // 65536 floats (offset 16640 B, 16B-aligned)

    k1_gemv<<<K1_BLOCKS, 256, 0, stream>>>(P, H, PH, partial);
    k2_reduce<<<1, 256, 0, stream>>>(partial, tmp);
    const unsigned total4 = (NROWS / 4) + (NROWS * (NN / 4)); // 16384 + 33554432
    k3_update<<<total4 / 256, 256, 0, stream>>>(P, w, err, PH, tmp, out);
}